// Round 5
// baseline (4014.259 us; speedup 1.0000x reference)
//
#include <hip/hip_runtime.h>

// ---------------- problem constants ----------------
#define BB 16          // batch
#define SS 64          // seq
#define HH 512         // hidden
#define MR (BB*SS)     // 1024 rows of (b,s)
#define GN (4*HH)      // 2048 gate cols
#define NLAYER 4
#define OUTD 10
#define LBLK 16        // blocks per layer (each owns 32 h-cols)
// ring slots: layers 0..2 are FULL-depth (64 slots each -> a producer slot is
// NEVER reused within a dispatch => no backpressure needed, no cross-layer
// reuse races). Layer 3 has no downstream consumer; its own recurrence only
// needs the round-1-proven 2-deep ring.
#define NSLOT (3*SS + 2)

typedef float   floatx4  __attribute__((ext_vector_type(4)));
typedef __bf16  bf16x8   __attribute__((ext_vector_type(8)));
typedef unsigned short ushort8v __attribute__((ext_vector_type(8)));
typedef int     intx4    __attribute__((ext_vector_type(4)));

#define MFMA_BF16(a,b,c) __builtin_amdgcn_mfma_f32_16x16x32_bf16((a),(b),(c),0,0,0)

static __device__ __forceinline__ unsigned short f2bf_rne(float f) {
  union { float f; unsigned u; } v; v.f = f;
  unsigned r = v.u + 0x7fffu + ((v.u >> 16) & 1u);
  return (unsigned short)(r >> 16);
}

// load 8 consecutive fp32 and round to a bf16x8 MFMA fragment
static __device__ __forceinline__ bf16x8 load_a8(const float* __restrict__ p) {
  float4 x0 = *(const float4*)p;
  float4 x1 = *(const float4*)(p + 4);
  union { ushort8v u; bf16x8 b; } c;
  c.u[0] = f2bf_rne(x0.x); c.u[1] = f2bf_rne(x0.y);
  c.u[2] = f2bf_rne(x0.z); c.u[3] = f2bf_rne(x0.w);
  c.u[4] = f2bf_rne(x1.x); c.u[5] = f2bf_rne(x1.y);
  c.u[6] = f2bf_rne(x1.z); c.u[7] = f2bf_rne(x1.w);
  return c.b;
}

// fast gate activations: v_exp + v_rcp, correct saturation at +/-inf
static __device__ __forceinline__ float sigm(float x) {
  return __builtin_amdgcn_rcpf(1.f + __expf(-x));
}
static __device__ __forceinline__ float tanh_fast(float x) {
  return 1.f - 2.f * __builtin_amdgcn_rcpf(1.f + __expf(2.f * x));
}

// device-coherent (bypass L1/L2 to the coherent point) loads/stores
static __device__ __forceinline__ intx4 coh_load16(const void* p) {
  intx4 r;
  asm volatile("global_load_dwordx4 %0, %1, off sc0 sc1"
               : "=v"(r) : "v"(p) : "memory");
  return r;
}
static __device__ __forceinline__ void coh_store_dword(void* p, unsigned v) {
  asm volatile("global_store_dword %0, %1, off sc0 sc1"
               :: "v"(p), "v"(v) : "memory");
}
static __device__ __forceinline__ void wait_vm0() {
  asm volatile("s_waitcnt vmcnt(0)" ::: "memory");
}

// ---------------- utility kernels ----------------
__global__ void hrm_zero_f32(float* p, int n) {
  int i = blockIdx.x * 256 + threadIdx.x;
  if (i < n) p[i] = 0.f;
}
__global__ void hrm_zero_u16(unsigned short* p, int n) {
  int i = blockIdx.x * 256 + threadIdx.x;
  if (i < n) p[i] = 0;
}
__global__ void hrm_cvt_bf16(unsigned short* __restrict__ dst,
                             const float* __restrict__ src, int n) {
  int i = blockIdx.x * 256 + threadIdx.x;
  if (i < n) dst[i] = f2bf_rne(src[i]);
}
__global__ void hrm_addvec(float* __restrict__ o, const float* __restrict__ a,
                           const float* __restrict__ b, int n) {
  int i = blockIdx.x * 256 + threadIdx.x;
  if (i < n) o[i] = a[i] + b[i];
}

// ---------------- generic MFMA GEMM: C[M,N] = A[M,K] @ W[N,K]^T (+epilogue) ----
// grid = (ceil(N/64), M/16), block = 64 (1 wave). Wave tile 16(M) x 64(N).
__global__ __launch_bounds__(64) void hrm_gemm16(
    const float* __restrict__ A, const unsigned short* __restrict__ W,
    float* __restrict__ C, const float* __restrict__ bias0,
    const float* __restrict__ bias1, const float* __restrict__ res0,
    const float* __restrict__ res1, int N, int K, int relu, int out_bf16)
{
  const int lane  = threadIdx.x;
  const int mrow  = lane & 15;
  const int kq    = lane >> 4;
  const int m_base = blockIdx.y << 4;
  const int n_base = blockIdx.x << 6;

  floatx4 acc[4] = {{0.f,0.f,0.f,0.f},{0.f,0.f,0.f,0.f},
                    {0.f,0.f,0.f,0.f},{0.f,0.f,0.f,0.f}};
  const float* ap = A + (size_t)(m_base + mrow) * K + kq * 8;
  const unsigned short* wp = W + (size_t)(n_base + mrow) * K + kq * 8;

  #pragma unroll 4
  for (int kt = 0; kt < K; kt += 32) {
    bf16x8 a = load_a8(ap + kt);
    #pragma unroll
    for (int sub = 0; sub < 4; ++sub) {
      bf16x8 b = *(const bf16x8*)(wp + (size_t)sub * 16 * K + kt);
      acc[sub] = MFMA_BF16(a, b, acc[sub]);
    }
  }
  // C/D layout: col = lane&15, row = (lane>>4)*4 + r  [verified m89/m91]
  #pragma unroll
  for (int sub = 0; sub < 4; ++sub) {
    int n = n_base + sub * 16 + mrow;
    if (n < N) {
      #pragma unroll
      for (int r = 0; r < 4; ++r) {
        int m = m_base + kq * 4 + r;
        size_t idx = (size_t)m * N + n;
        float v = acc[sub][r];
        if (bias0) v += bias0[n];
        if (bias1) v += bias1[n];
        if (res0)  v += res0[idx];
        if (res1)  v += res1[idx];
        if (relu)  v = fmaxf(v, 0.f);
        if (out_bf16) ((unsigned short*)C)[idx] = f2bf_rne(v);
        else          C[idx] = v;
      }
    }
  }
}

// ---------------- fused 4-layer pipelined LSTM stack ----------------
// 64 blocks = 4 layers x 16 col-slices (32 h-cols each; round-1-verified
// per-layer geometry -> fewer producers per layer = less straggler
// amplification, fewer pollers = less coherent-fabric flood than the
// 128-block round-4 variant). Each block computes x_t @ Wih slice +
// h(t-1) @ Whh slice via MFMA; weight slices nominally in registers
// (compiler may rematerialize from L1 -- harmless, round-1/4 verified).
//
// Dataflow: layer l publishes h(t) as tagged u32 words ((tag<<16)|bf16(h),
// tag = sibase+t+1) into ring slot t of its ring; layer l+1 polls the exact
// tag -- the successful poll IS the data load. Layers 0..2 rings are 64-deep
// => slots write-once per dispatch => NO backpressure. Layer 3's ring is
// 2-deep (own recurrence only).
// Layer 0 reads x from a plain bf16 buffer (ready before launch).
//
// hbuf is zeroed each call => no stale tags from previous calls/replays.
// Safety net: persistent per-thread spin budget; on depletion polls break
// (wrong answer but TERMINATES -> counters instead of a hang).
__global__ __launch_bounds__(256, 1) void hrm_stack(
    const unsigned short* __restrict__ xin,   // (1024,512) bf16 layer-0 input
    const unsigned short* __restrict__ Wih,   // (4,2048,512) bf16
    const unsigned short* __restrict__ Whh,   // (4,2048,512) bf16
    const float* __restrict__ bsum,           // (4,2048) bih+bhh
    float* __restrict__ Y,                    // (1024,512) final-layer output
    int* __restrict__ hb,                     // (NSLOT,16,512) tagged u32
    int sibase)
{
  __shared__ unsigned short hs_x[BB][520];   // staged x_t (layers 1-3)
  __shared__ unsigned short hs_h[BB][520];   // staged h(t-1)
  __shared__ float gt[4][BB][32];            // gate pre-activations
  __shared__ float cst[BB][32];              // cell state (per-thread cells)

  const int tid  = threadIdx.x;
  const int bid  = blockIdx.x;
  const int l    = bid >> 4;                 // layer 0..3
  const int sub  = bid & 15;                 // col-slice 0..15 (32 cols)
  const int lane = tid & 63;
  const int w    = tid >> 6;                 // gate 0..3 (i,f,g,o)
  const int mrow = lane & 15;
  const int kq   = lane >> 4;
  const int b    = tid >> 4;                 // epilogue batch
  const int j0   = tid & 15;                 // epilogue col base

  cst[b][j0] = 0.f; cst[b][j0 + 16] = 0.f;

  // ---- weight slices into registers (once per dispatch) ----
  // wave rows: n = w*512 + sub*32 + {mrow, 16+mrow}; frag k-off kq*8 + kt*32
  bf16x8 wif[2][16], whf[2][16];
  {
    const size_t rowoff = (size_t)(w * HH + sub * 32 + mrow) * HH + kq * 8;
    const unsigned short* p = Wih + (size_t)l * GN * HH + rowoff;
    const unsigned short* q = Whh + (size_t)l * GN * HH + rowoff;
    #pragma unroll
    for (int kt = 0; kt < 16; ++kt) {
      wif[0][kt] = *(const bf16x8*)(p + kt * 32);
      wif[1][kt] = *(const bf16x8*)(p + (size_t)16 * HH + kt * 32);
      whf[0][kt] = *(const bf16x8*)(q + kt * 32);
      whf[1][kt] = *(const bf16x8*)(q + (size_t)16 * HH + kt * 32);
    }
  }
  // ---- bias (bih+bhh) for this thread's epilogue cells ----
  float bias_v[2][4];
  #pragma unroll
  for (int qq = 0; qq < 2; ++qq)
    #pragma unroll
    for (int w2 = 0; w2 < 4; ++w2)
      bias_v[qq][w2] = bsum[l * GN + w2 * HH + sub * 32 + j0 + qq * 16];

  // ring bases: layer l's ring starts at slot l*64 (layer 3 uses 2 slots)
  int* myhb = hb + (size_t)l * SS * BB * HH;
  const bool needx = (l > 0);
  const int* xhb = needx ? (hb + (size_t)(l - 1) * SS * BB * HH) : hb;

  int spin_budget = 1 << 17;   // persistent across steps; never hit if correct

  for (int t = 0; t < SS; ++t) {
    const bool needh = (t > 0);
    const int wr_slot = (l == 3) ? (t & 1) : t;

    // layer 0: pre-issue x fragment loads (plain cached loads)
    bf16x8 ax0[16];
    if (l == 0) {
      const unsigned short* xr = xin + (size_t)(mrow * SS + t) * HH + kq * 8;
      #pragma unroll
      for (int kt = 0; kt < 16; ++kt) ax0[kt] = *(const bf16x8*)(xr + kt * 32);
    }

    // ---- fused poll+load of x_t (layer l-1 ring) and h(t-1) (own ring) ----
    if (needx || needh) {
      const unsigned xtag = (unsigned)(sibase + t + 1);
      const unsigned htag = (unsigned)(sibase + t);
      const int rd_slot = (l == 3) ? ((t - 1) & 1) : (t - 1);
      const int* xp = xhb + (size_t)t * BB * HH + tid * 32;
      const int* hp = myhb + (size_t)rd_slot * BB * HH + tid * 32;
      intx4 sx[8], sh[8];
      int fails = 0;
      for (;;) {
        if (needx) {
          #pragma unroll
          for (int k = 0; k < 8; ++k) sx[k] = coh_load16(xp + k * 4);
        }
        if (needh) {
          #pragma unroll
          for (int k = 0; k < 8; ++k) sh[k] = coh_load16(hp + k * 4);
        }
        wait_vm0();
        __builtin_amdgcn_sched_barrier(0);   // rule-18: no hoist past waitcnt
        unsigned bad = 0;
        if (needx) {
          #pragma unroll
          for (int k = 0; k < 8; ++k)
            #pragma unroll
            for (int i = 0; i < 4; ++i)
              bad |= ((unsigned)sx[k][i] >> 16) ^ xtag;
        }
        if (needh) {
          #pragma unroll
          for (int k = 0; k < 8; ++k)
            #pragma unroll
            for (int i = 0; i < 4; ++i)
              bad |= ((unsigned)sh[k][i] >> 16) ^ htag;
        }
        if (bad == 0) break;
        if (--spin_budget < 0) break;        // terminate instead of hang
        if (++fails > 16) __builtin_amdgcn_s_sleep(8);  // flood relief
      }
      // strip tags, pack bf16 pairs, stage to LDS (thread owns 32 words)
      const int srow  = tid >> 4;
      const int scol0 = (tid & 15) * 32;
      if (needx) {
        #pragma unroll
        for (int k = 0; k < 8; k += 2) {
          intx4 lo = sx[k], hi = sx[k + 1], pk;
          pk[0] = (lo[0] & 0xffff) | (lo[1] << 16);
          pk[1] = (lo[2] & 0xffff) | (lo[3] << 16);
          pk[2] = (hi[0] & 0xffff) | (hi[1] << 16);
          pk[3] = (hi[2] & 0xffff) | (hi[3] << 16);
          *(intx4*)&hs_x[srow][scol0 + k * 4] = pk;
        }
      }
      if (needh) {
        #pragma unroll
        for (int k = 0; k < 8; k += 2) {
          intx4 lo = sh[k], hi = sh[k + 1], pk;
          pk[0] = (lo[0] & 0xffff) | (lo[1] << 16);
          pk[1] = (lo[2] & 0xffff) | (lo[3] << 16);
          pk[2] = (hi[0] & 0xffff) | (hi[1] << 16);
          pk[3] = (hi[2] & 0xffff) | (hi[3] << 16);
          *(intx4*)&hs_h[srow][scol0 + k * 4] = pk;
        }
      }
    }
    __syncthreads();   // hs_x/hs_h ready; prior-step gt reads complete

    // ---- gates: x_t @ Wih^T + h(t-1) @ Whh^T, 2 col-groups ----
    floatx4 a0 = {0.f,0.f,0.f,0.f}, a1 = {0.f,0.f,0.f,0.f};
    if (l == 0) {
      #pragma unroll
      for (int kt = 0; kt < 16; ++kt) {
        a0 = MFMA_BF16(ax0[kt], wif[0][kt], a0);
        a1 = MFMA_BF16(ax0[kt], wif[1][kt], a1);
      }
    } else {
      const unsigned short* xr = &hs_x[mrow][kq * 8];
      #pragma unroll
      for (int kt = 0; kt < 16; ++kt) {
        bf16x8 a = *(const bf16x8*)(xr + kt * 32);
        a0 = MFMA_BF16(a, wif[0][kt], a0);
        a1 = MFMA_BF16(a, wif[1][kt], a1);
      }
    }
    if (needh) {
      const unsigned short* hr = &hs_h[mrow][kq * 8];
      #pragma unroll
      for (int kt = 0; kt < 16; ++kt) {
        bf16x8 a = *(const bf16x8*)(hr + kt * 32);
        a0 = MFMA_BF16(a, whf[0][kt], a0);
        a1 = MFMA_BF16(a, whf[1][kt], a1);
      }
    }
    #pragma unroll
    for (int r = 0; r < 4; ++r) {
      gt[w][kq * 4 + r][mrow]      = a0[r];
      gt[w][kq * 4 + r][16 + mrow] = a1[r];
    }
    __syncthreads();   // gt ready; hs reads complete

    // ---- epilogue: 16 batches x 32 cols (2 cells/thread) ----
    const unsigned tag = (unsigned)(sibase + t + 1) << 16;
    int* hb_cur = myhb + (size_t)wr_slot * BB * HH;
    #pragma unroll
    for (int q = 0; q < 2; ++q) {
      int jj = j0 + q * 16;
      int n  = sub * 32 + jj;
      float gi = gt[0][b][jj] + bias_v[q][0];
      float gf = gt[1][b][jj] + bias_v[q][1];
      float gg = gt[2][b][jj] + bias_v[q][2];
      float go = gt[3][b][jj] + bias_v[q][3];
      float ig = sigm(gi), fg = sigm(gf), gvv = tanh_fast(gg), og = sigm(go);
      float c = fg * cst[b][jj] + ig * gvv;
      cst[b][jj] = c;
      float h = og * tanh_fast(c);
      coh_store_dword(hb_cur + b * HH + n, tag | (unsigned)f2bf_rne(h));
      if (l == 3) Y[(size_t)(b * SS + t) * HH + n] = h;
    }
    // no trailing barrier: next staging (hs writes) is ordered after this
    // step's MFMA hs-reads by the post-MFMA barrier; epilogue gt reads are
    // ordered before next MFMA gt writes by the next staging barrier.
  }
}

// ---------------- LayerNorm over concat([low, high]) ----------------
__global__ __launch_bounds__(256) void hrm_ln(
    const float* __restrict__ low, const float* __restrict__ high,
    const float* __restrict__ g, const float* __restrict__ bta,
    float* __restrict__ out)
{
  __shared__ float sa[256], sb[256];
  const int row = blockIdx.x;   // 0..1023
  const int tid = threadIdx.x;
  float vals[4], s = 0.f, s2 = 0.f;
  #pragma unroll
  for (int i = 0; i < 4; ++i) {
    int c = tid + i * 256;
    float v = (c < HH) ? low[(size_t)row * HH + c]
                       : high[(size_t)row * HH + (c - HH)];
    vals[i] = v; s += v; s2 += v * v;
  }
  sa[tid] = s; sb[tid] = s2; __syncthreads();
  for (int off = 128; off > 0; off >>= 1) {
    if (tid < off) { sa[tid] += sa[tid + off]; sb[tid] += sb[tid + off]; }
    __syncthreads();
  }
  float mu  = sa[0] * (1.f / 1024.f);
  float var = sb[0] * (1.f / 1024.f) - mu * mu;
  float rstd = rsqrtf(var + 1e-5f);
  #pragma unroll
  for (int i = 0; i < 4; ++i) {
    int c = tid + i * 256;
    out[(size_t)row * 1024 + c] = (vals[i] - mu) * rstd * g[c] + bta[c];
  }
}

// ---------------- host orchestration ----------------
extern "C" void kernel_launch(void* const* d_in, const int* in_sizes, int n_in,
                              void* d_out, int out_size, void* d_ws, size_t ws_size,
                              hipStream_t stream) {
  const float* x        = (const float*)d_in[0];
  const float* Wp_in    = (const float*)d_in[1];
  const float* bp_in    = (const float*)d_in[2];
  const float* low_Wih  = (const float*)d_in[3];
  const float* low_Whh  = (const float*)d_in[4];
  const float* low_bih  = (const float*)d_in[5];
  const float* low_bhh  = (const float*)d_in[6];
  const float* high_Wih = (const float*)d_in[7];
  const float* high_Whh = (const float*)d_in[8];
  const float* high_bih = (const float*)d_in[9];
  const float* high_bhh = (const float*)d_in[10];
  const float* W_lowp   = (const float*)d_in[11];
  const float* W_highp  = (const float*)d_in[12];
  const float* ln_g     = (const float*)d_in[13];
  const float* ln_b     = (const float*)d_in[14];
  const float* W1       = (const float*)d_in[15];
  const float* b1       = (const float*)d_in[16];
  const float* W2       = (const float*)d_in[17];
  const float* b2       = (const float*)d_in[18];
  const float* W3       = (const float*)d_in[19];
  const float* b3       = (const float*)d_in[20];

  char* wsp = (char*)d_ws;
  size_t off = 0;
  auto alloc = [&](size_t bytes) -> void* {
    void* p = wsp + off;
    off += (bytes + 255) & ~(size_t)255;
    return p;
  };
  const size_t WSZ = (size_t)GN * HH;  // 2048*512 elems per layer matrix
  unsigned short* wp_b   = (unsigned short*)alloc(512u * 512u * 2);
  unsigned short* lwih_b = (unsigned short*)alloc(NLAYER * WSZ * 2);
  unsigned short* lwhh_b = (unsigned short*)alloc(NLAYER * WSZ * 2);
  unsigned short* hwih_b = (unsigned short*)alloc(NLAYER * WSZ * 2);
  unsigned short* hwhh_b = (unsigned short*)alloc(NLAYER * WSZ * 2);
  unsigned short* wlp_b  = (unsigned short*)alloc(512u * 512u * 2);
  unsigned short* whp_b  = (unsigned short*)alloc(512u * 512u * 2);
  unsigned short* w1_b   = (unsigned short*)alloc(512u * 1024u * 2);
  unsigned short* w2_b   = (unsigned short*)alloc(256u * 512u * 2);
  unsigned short* w3p_b  = (unsigned short*)alloc(64u * 256u * 2);   // padded

  float* bsum_l = (float*)alloc(NLAYER * GN * 4);
  float* bsum_h = (float*)alloc(NLAYER * GN * 4);

  float* emb    = (float*)alloc((size_t)MR * HH * 4);
  float* lowb   = (float*)alloc((size_t)MR * HH * 4);
  float* highb  = (float*)alloc((size_t)MR * HH * 4);
  float* xa     = (float*)alloc((size_t)MR * HH * 4);
  float* xb     = (float*)alloc((size_t)MR * HH * 4);
  int* hbuf = (int*)alloc((size_t)NSLOT * BB * HH * 4);
  // aliases (lifetimes disjoint; keeps total ws <= round-1-proven budget):
  //  - comb (bf16 GEMM output / stack input) lives in xa; xa's fp32 use is
  //    only after the last hrm_stack.
  //  - normed (LN output) lives in hbuf; written only after the last stack.
  unsigned short* comb = (unsigned short*)xa;
  float* normed = (float*)hbuf;

  auto cvt = [&](unsigned short* dst, const float* src, int n) {
    hrm_cvt_bf16<<<(n + 255) / 256, 256, 0, stream>>>(dst, src, n);
  };
  cvt(wp_b,   Wp_in,    512 * 512);
  cvt(lwih_b, low_Wih,  (int)(NLAYER * WSZ));
  cvt(lwhh_b, low_Whh,  (int)(NLAYER * WSZ));
  cvt(hwih_b, high_Wih, (int)(NLAYER * WSZ));
  cvt(hwhh_b, high_Whh, (int)(NLAYER * WSZ));
  cvt(wlp_b,  W_lowp,   512 * 512);
  cvt(whp_b,  W_highp,  512 * 512);
  cvt(w1_b,   W1,       512 * 1024);
  cvt(w2_b,   W2,       256 * 512);
  hrm_zero_u16<<<(64 * 256 + 255) / 256, 256, 0, stream>>>(w3p_b, 64 * 256);
  cvt(w3p_b, W3, OUTD * 256);

  hrm_addvec<<<(NLAYER * GN + 255) / 256, 256, 0, stream>>>(
      bsum_l, low_bih, low_bhh, NLAYER * GN);
  hrm_addvec<<<(NLAYER * GN + 255) / 256, 256, 0, stream>>>(
      bsum_h, high_bih, high_bhh, NLAYER * GN);

  // zero-init state + ring buffers (ws poisoned 0xAA each call; zeroing the
  // ring also wipes previous-replay tags so pacing semantics stay strict)
  hrm_zero_f32<<<(MR * HH + 255) / 256, 256, 0, stream>>>(lowb,  MR * HH);
  hrm_zero_f32<<<(MR * HH + 255) / 256, 256, 0, stream>>>(highb, MR * HH);
  hrm_zero_f32<<<(NSLOT * BB * HH + 255) / 256, 256, 0, stream>>>(
      (float*)hbuf, NSLOT * BB * HH);

  // emb = x @ Wp_in^T + bp_in
  hrm_gemm16<<<dim3(HH / 64, MR / 16), 64, 0, stream>>>(
      x, wp_b, emb, bp_in, nullptr, nullptr, nullptr, HH, HH, 0, 0);

  const int seq[10] = {0, 0, 0, 0, 1, 0, 0, 0, 0, 1};
  for (int si = 0; si < 10; ++si) {
    const bool hi = seq[si] != 0;
    float* target = hi ? highb : lowb;
    const float* first  = target;
    const float* second = hi ? lowb : highb;
    const unsigned short* proj = hi ? whp_b : wlp_b;

    // combined = second @ Wproj^T + first + emb   (written directly as bf16)
    hrm_gemm16<<<dim3(HH / 64, MR / 16), 64, 0, stream>>>(
        second, proj, (float*)comb, nullptr, nullptr, first, emb, HH, HH, 0, 1);

    // fused, pipelined 4-layer LSTM stack
    hrm_stack<<<NLAYER * LBLK, 256, 0, stream>>>(
        comb, hi ? hwih_b : lwih_b, hi ? hwhh_b : lwhh_b,
        hi ? bsum_h : bsum_l, target, hbuf, si * 64);
  }

  // LayerNorm(concat) -> MLP
  hrm_ln<<<MR, 256, 0, stream>>>(lowb, highb, ln_g, ln_b, normed);
  hrm_gemm16<<<dim3(HH / 64, MR / 16), 64, 0, stream>>>(
      normed, w1_b, xa, b1, nullptr, nullptr, nullptr, HH, 2 * HH, 1, 0);
  hrm_gemm16<<<dim3(256 / 64, MR / 16), 64, 0, stream>>>(
      xa, w2_b, xb, b2, nullptr, nullptr, nullptr, 256, HH, 1, 0);
  hrm_gemm16<<<dim3(1, MR / 16), 64, 0, stream>>>(
      xb, w3p_b, (float*)d_out, b3, nullptr, nullptr, nullptr, OUTD, 256, 0, 0);
  (void)in_sizes; (void)n_in; (void)out_size; (void)ws_size;
}

// Round 6
// 3574.770 us; speedup vs baseline: 1.1229x; 1.1229x over previous
//
#include <hip/hip_runtime.h>

// ---------------- problem constants ----------------
#define BB 16          // batch
#define SS 64          // seq
#define HH 512         // hidden
#define MR (BB*SS)     // 1024 rows of (b,s)
#define GN (4*HH)      // 2048 gate cols
#define NLAYER 4
#define OUTD 10
#define LBLK 32        // blocks per layer (round-4 proven: 16 cols each, VGPR 164)
#define NSLOT (4*SS)   // ALL layer rings full-depth (64 slots, write-once per si)

typedef float   floatx4  __attribute__((ext_vector_type(4)));
typedef __bf16  bf16x8   __attribute__((ext_vector_type(8)));
typedef unsigned short ushort8v __attribute__((ext_vector_type(8)));
typedef int     intx4    __attribute__((ext_vector_type(4)));

#define MFMA_BF16(a,b,c) __builtin_amdgcn_mfma_f32_16x16x32_bf16((a),(b),(c),0,0,0)

static __device__ __forceinline__ unsigned short f2bf_rne(float f) {
  union { float f; unsigned u; } v; v.f = f;
  unsigned r = v.u + 0x7fffu + ((v.u >> 16) & 1u);
  return (unsigned short)(r >> 16);
}
static __device__ __forceinline__ float bf2f(unsigned w) {
  union { unsigned u; float f; } c; c.u = w << 16; return c.f;
}

// load 8 consecutive fp32 and round to a bf16x8 MFMA fragment
static __device__ __forceinline__ bf16x8 load_a8(const float* __restrict__ p) {
  float4 x0 = *(const float4*)p;
  float4 x1 = *(const float4*)(p + 4);
  union { ushort8v u; bf16x8 b; } c;
  c.u[0] = f2bf_rne(x0.x); c.u[1] = f2bf_rne(x0.y);
  c.u[2] = f2bf_rne(x0.z); c.u[3] = f2bf_rne(x0.w);
  c.u[4] = f2bf_rne(x1.x); c.u[5] = f2bf_rne(x1.y);
  c.u[6] = f2bf_rne(x1.z); c.u[7] = f2bf_rne(x1.w);
  return c.b;
}

// fast gate activations: v_exp + v_rcp, correct saturation at +/-inf
static __device__ __forceinline__ float sigm(float x) {
  return __builtin_amdgcn_rcpf(1.f + __expf(-x));
}
static __device__ __forceinline__ float tanh_fast(float x) {
  return 1.f - 2.f * __builtin_amdgcn_rcpf(1.f + __expf(2.f * x));
}

// device-coherent (bypass L1/L2 to the coherent point) loads/stores
static __device__ __forceinline__ intx4 coh_load16(const void* p) {
  intx4 r;
  asm volatile("global_load_dwordx4 %0, %1, off sc0 sc1"
               : "=v"(r) : "v"(p) : "memory");
  return r;
}
static __device__ __forceinline__ unsigned coh_load4(const void* p) {
  unsigned r;
  asm volatile("global_load_dword %0, %1, off sc0 sc1"
               : "=v"(r) : "v"(p) : "memory");
  return r;
}
static __device__ __forceinline__ void coh_store_dword(void* p, unsigned v) {
  asm volatile("global_store_dword %0, %1, off sc0 sc1"
               :: "v"(p), "v"(v) : "memory");
}
static __device__ __forceinline__ void wait_vm0() {
  asm volatile("s_waitcnt vmcnt(0)" ::: "memory");
}

// ---------------- utility kernels ----------------
__global__ void hrm_zero_f32(float* p, int n) {
  int i = blockIdx.x * 256 + threadIdx.x;
  if (i < n) p[i] = 0.f;
}
__global__ void hrm_zero_u16(unsigned short* p, int n) {
  int i = blockIdx.x * 256 + threadIdx.x;
  if (i < n) p[i] = 0;
}
__global__ void hrm_cvt_bf16(unsigned short* __restrict__ dst,
                             const float* __restrict__ src, int n) {
  int i = blockIdx.x * 256 + threadIdx.x;
  if (i < n) dst[i] = f2bf_rne(src[i]);
}
__global__ void hrm_addvec(float* __restrict__ o, const float* __restrict__ a,
                           const float* __restrict__ b, int n) {
  int i = blockIdx.x * 256 + threadIdx.x;
  if (i < n) o[i] = a[i] + b[i];
}

// ---------------- generic MFMA GEMM: C[M,N] = A[M,K] @ W[N,K]^T (+epilogue) ----
// grid = (ceil(N/64), M/16), block = 64 (1 wave). Wave tile 16(M) x 64(N).
__global__ __launch_bounds__(64) void hrm_gemm16(
    const float* __restrict__ A, const unsigned short* __restrict__ W,
    float* __restrict__ C, const float* __restrict__ bias0,
    const float* __restrict__ bias1, const float* __restrict__ res0,
    const float* __restrict__ res1, int N, int K, int relu, int out_bf16)
{
  const int lane  = threadIdx.x;
  const int mrow  = lane & 15;
  const int kq    = lane >> 4;
  const int m_base = blockIdx.y << 4;
  const int n_base = blockIdx.x << 6;

  floatx4 acc[4] = {{0.f,0.f,0.f,0.f},{0.f,0.f,0.f,0.f},
                    {0.f,0.f,0.f,0.f},{0.f,0.f,0.f,0.f}};
  const float* ap = A + (size_t)(m_base + mrow) * K + kq * 8;
  const unsigned short* wp = W + (size_t)(n_base + mrow) * K + kq * 8;

  #pragma unroll 4
  for (int kt = 0; kt < K; kt += 32) {
    bf16x8 a = load_a8(ap + kt);
    #pragma unroll
    for (int sub = 0; sub < 4; ++sub) {
      bf16x8 b = *(const bf16x8*)(wp + (size_t)sub * 16 * K + kt);
      acc[sub] = MFMA_BF16(a, b, acc[sub]);
    }
  }
  // C/D layout: col = lane&15, row = (lane>>4)*4 + r  [verified m89/m91]
  #pragma unroll
  for (int sub = 0; sub < 4; ++sub) {
    int n = n_base + sub * 16 + mrow;
    if (n < N) {
      #pragma unroll
      for (int r = 0; r < 4; ++r) {
        int m = m_base + kq * 4 + r;
        size_t idx = (size_t)m * N + n;
        float v = acc[sub][r];
        if (bias0) v += bias0[n];
        if (bias1) v += bias1[n];
        if (res0)  v += res0[idx];
        if (res1)  v += res1[idx];
        if (relu)  v = fmaxf(v, 0.f);
        if (out_bf16) ((unsigned short*)C)[idx] = f2bf_rne(v);
        else          C[idx] = v;
      }
    }
  }
}

// ---------------- fused 4-layer pipelined LSTM stack + comb tail ----------------
// 128 blocks = 4 layers x 32 col-slices (round-4 proven geometry: 16 h-cols,
// wif[16]+whf[16] = 128 weight VGPRs/lane -> truly register-resident,
// VGPR_Count 164; round-5's 2x slices demanded 256 -> remat -> slower).
//
// Main loop: tag-ring pipeline (round-4 proven). Layer l publishes h(t) as
// tagged u32 ((tag<<16)|bf16, tag=sibase+t+1) into slot t of its 64-deep
// ring; consumers poll exact tags -- the successful poll IS the data load.
// Rings write-once per dispatch => no backpressure. Poll split: x-ring first
// (steady-state ready in ~1 sweep), then the critical h-poll with half the
// loads per sweep (finer detection quantum on the recurrence chain).
//
// Tail (NEW): computes comb for the NEXT si in-kernel, replacing the separate
// proj GEMM dispatch: comb = first + second @ Wproj^T + emb, 512 wave-jobs
// (= gemm16 tiling of 1024x512). The freshly-produced state is read from the
// tagged L3 ring (poll-verified); the other state from a stable bf16 buffer
// (written by an EARLIER dispatch's L3 plain stores -- never this dispatch's
// type, so no same-dispatch visibility hazard). Output comb/state16 via plain
// stores, read only by later dispatches (boundary-coherent).
__global__ __launch_bounds__(256, 1) void hrm_stack(
    const unsigned short* __restrict__ xin,   // (1024,512) bf16 comb input
    const unsigned short* __restrict__ Wih,   // (4,2048,512) bf16
    const unsigned short* __restrict__ Whh,   // (4,2048,512) bf16
    const float* __restrict__ bsum,           // (4,2048) bih+bhh
    float* __restrict__ Y,                    // fp32 state out (final si only)
    unsigned short* __restrict__ state16,     // bf16 state out (always)
    int* __restrict__ hb,                     // (NSLOT,16,512) tagged u32
    int sibase,
    // tail params:
    const unsigned short* __restrict__ projw, // (512,512) bf16 Wproj (next si)
    const unsigned short* __restrict__ tfirst,  // stable bf16 or null(=ring)
    const unsigned short* __restrict__ tsecond, // stable bf16 or null(=ring)
    const float* __restrict__ emb,            // (1024,512) fp32
    unsigned short* __restrict__ comb_out)    // (1024,512) bf16, null=skip
{
  __shared__ unsigned short hs_x[BB][520];   // staged x_t (layers 1-3)
  __shared__ unsigned short hs_h[BB][520];   // staged h(t-1)
  __shared__ float gt[4][BB][16];            // gate pre-activations
  __shared__ float cst[BB][16];              // cell state (per-thread cells)

  const int tid  = threadIdx.x;
  const int bid  = blockIdx.x;
  const int l    = bid >> 5;                 // layer 0..3
  const int sub  = bid & 31;                 // col-slice 0..31 (16 cols)
  const int lane = tid & 63;
  const int w    = tid >> 6;                 // gate 0..3 (i,f,g,o)
  const int mrow = lane & 15;
  const int kq   = lane >> 4;
  const int b    = tid >> 4;                 // epilogue batch
  const int j0   = tid & 15;                 // epilogue col

  cst[b][j0] = 0.f;

  // ---- weight slices into registers (once per dispatch) ----
  bf16x8 wif[16], whf[16];
  {
    const size_t rowoff = (size_t)(w * HH + sub * 16 + mrow) * HH + kq * 8;
    const unsigned short* p = Wih + (size_t)l * GN * HH + rowoff;
    const unsigned short* q = Whh + (size_t)l * GN * HH + rowoff;
    #pragma unroll
    for (int kt = 0; kt < 16; ++kt) {
      wif[kt] = *(const bf16x8*)(p + kt * 32);
      whf[kt] = *(const bf16x8*)(q + kt * 32);
    }
  }
  float bias_v[4];
  #pragma unroll
  for (int w2 = 0; w2 < 4; ++w2)
    bias_v[w2] = bsum[l * GN + w2 * HH + sub * 16 + j0];

  int* myhb = hb + (size_t)l * SS * BB * HH;
  const bool needx = (l > 0);
  const int* xhb = needx ? (hb + (size_t)(l - 1) * SS * BB * HH) : hb;

  int spin_budget = 1 << 17;   // persistent; never hit if protocol correct

  for (int t = 0; t < SS; ++t) {
    const bool needh = (t > 0);

    // layer 0: pre-issue x fragment loads (plain cached loads)
    bf16x8 ax0[16];
    if (l == 0) {
      const unsigned short* xr = xin + (size_t)(mrow * SS + t) * HH + kq * 8;
      #pragma unroll
      for (int kt = 0; kt < 16; ++kt) ax0[kt] = *(const bf16x8*)(xr + kt * 32);
    }

    const int srow  = tid >> 4;
    const int scol0 = (tid & 15) * 32;

    // ---- poll+load x_t from layer l-1 ring (steady-state: ~1 sweep) ----
    if (needx) {
      const unsigned xtag = (unsigned)(sibase + t + 1);
      const int* xp = xhb + (size_t)t * BB * HH + tid * 32;
      intx4 sx[8];
      int fails = 0;
      for (;;) {
        #pragma unroll
        for (int k = 0; k < 8; ++k) sx[k] = coh_load16(xp + k * 4);
        wait_vm0();
        __builtin_amdgcn_sched_barrier(0);   // rule-18: no hoist past waitcnt
        unsigned bad = 0;
        #pragma unroll
        for (int k = 0; k < 8; ++k)
          #pragma unroll
          for (int i = 0; i < 4; ++i)
            bad |= ((unsigned)sx[k][i] >> 16) ^ xtag;
        if (bad == 0) break;
        if (--spin_budget < 0) break;        // terminate instead of hang
        if (++fails > 16) __builtin_amdgcn_s_sleep(8);
      }
      #pragma unroll
      for (int k = 0; k < 8; k += 2) {
        intx4 lo = sx[k], hi = sx[k + 1], pk;
        pk[0] = (lo[0] & 0xffff) | (lo[1] << 16);
        pk[1] = (lo[2] & 0xffff) | (lo[3] << 16);
        pk[2] = (hi[0] & 0xffff) | (hi[1] << 16);
        pk[3] = (hi[2] & 0xffff) | (hi[3] << 16);
        *(intx4*)&hs_x[srow][scol0 + k * 4] = pk;
      }
    }

    // ---- poll+load h(t-1) from own ring (the critical recurrence chain) ----
    if (needh) {
      const unsigned htag = (unsigned)(sibase + t);
      const int* hp = myhb + (size_t)(t - 1) * BB * HH + tid * 32;
      intx4 sh[8];
      int fails = 0;
      for (;;) {
        #pragma unroll
        for (int k = 0; k < 8; ++k) sh[k] = coh_load16(hp + k * 4);
        wait_vm0();
        __builtin_amdgcn_sched_barrier(0);
        unsigned bad = 0;
        #pragma unroll
        for (int k = 0; k < 8; ++k)
          #pragma unroll
          for (int i = 0; i < 4; ++i)
            bad |= ((unsigned)sh[k][i] >> 16) ^ htag;
        if (bad == 0) break;
        if (--spin_budget < 0) break;
        if (++fails > 16) __builtin_amdgcn_s_sleep(8);
      }
      #pragma unroll
      for (int k = 0; k < 8; k += 2) {
        intx4 lo = sh[k], hi = sh[k + 1], pk;
        pk[0] = (lo[0] & 0xffff) | (lo[1] << 16);
        pk[1] = (lo[2] & 0xffff) | (lo[3] << 16);
        pk[2] = (hi[0] & 0xffff) | (hi[1] << 16);
        pk[3] = (hi[2] & 0xffff) | (hi[3] << 16);
        *(intx4*)&hs_h[srow][scol0 + k * 4] = pk;
      }
    }
    __syncthreads();   // hs_x/hs_h ready; prior-step gt reads complete

    // ---- gates: two independent MFMA chains (x-part, h-part) ----
    floatx4 accx = {0.f,0.f,0.f,0.f}, acch = {0.f,0.f,0.f,0.f};
    if (l == 0) {
      #pragma unroll
      for (int kt = 0; kt < 16; ++kt) accx = MFMA_BF16(ax0[kt], wif[kt], accx);
    } else {
      const unsigned short* xr = &hs_x[mrow][kq * 8];
      #pragma unroll
      for (int kt = 0; kt < 16; ++kt) {
        bf16x8 a = *(const bf16x8*)(xr + kt * 32);
        accx = MFMA_BF16(a, wif[kt], accx);
      }
    }
    if (needh) {
      const unsigned short* hr = &hs_h[mrow][kq * 8];
      #pragma unroll
      for (int kt = 0; kt < 16; ++kt) {
        bf16x8 a = *(const bf16x8*)(hr + kt * 32);
        acch = MFMA_BF16(a, whf[kt], acch);
      }
    }
    floatx4 a0 = accx + acch;
    #pragma unroll
    for (int r = 0; r < 4; ++r) gt[w][kq * 4 + r][mrow] = a0[r];
    __syncthreads();   // gt ready; hs reads complete

    // ---- epilogue: 1 cell per thread (16 batches x 16 cols) ----
    const unsigned tag = (unsigned)(sibase + t + 1) << 16;
    int* hb_cur = myhb + (size_t)t * BB * HH;
    {
      int n = sub * 16 + j0;
      float gi = gt[0][b][j0] + bias_v[0];
      float gf = gt[1][b][j0] + bias_v[1];
      float gg = gt[2][b][j0] + bias_v[2];
      float go = gt[3][b][j0] + bias_v[3];
      float ig = sigm(gi), fg = sigm(gf), gvv = tanh_fast(gg), og = sigm(go);
      float c = fg * cst[b][j0] + ig * gvv;
      cst[b][j0] = c;
      float h = og * tanh_fast(c);
      coh_store_dword(hb_cur + b * HH + n, tag | (unsigned)f2bf_rne(h));
      if (l == 3) {
        size_t idx = (size_t)(b * SS + t) * HH + n;
        state16[idx] = f2bf_rne(h);         // plain store; next-dispatch read
        if (Y) Y[idx] = h;                  // fp32 for final LayerNorm
      }
    }
  }

  // ================= tail: comb for next si (replaces proj GEMM) ===========
  if (comb_out) {
    const int* ring3 = hb + (size_t)3 * SS * BB * HH;
    const int job    = bid * 4 + w;          // 512 wave-jobs
    const int m_base = (job >> 3) << 4;      // 64 row-tiles
    const int n_base = (job & 7) << 6;       // 8 col-tiles

    const int arow = m_base + mrow;          // this lane's A row
    const int ab   = arow >> 6, at = arow & 63;
    const unsigned atag = (unsigned)(sibase + at + 1);
    const int* aring = ring3 + ((size_t)at * BB + ab) * HH;

    floatx4 acc[4] = {{0.f,0.f,0.f,0.f},{0.f,0.f,0.f,0.f},
                      {0.f,0.f,0.f,0.f},{0.f,0.f,0.f,0.f}};
    const unsigned short* wp = projw + (size_t)(n_base + mrow) * HH + kq * 8;

    for (int kt = 0; kt < HH; kt += 32) {
      const int col = kq * 8 + kt;
      bf16x8 a;
      if (!tsecond) {
        // fresh state: tagged ring words (1 bf16 per dword)
        const int* p = aring + col;
        for (;;) {
          intx4 lo = coh_load16(p);
          intx4 hi = coh_load16(p + 4);
          wait_vm0();
          __builtin_amdgcn_sched_barrier(0);
          unsigned bad = 0;
          #pragma unroll
          for (int i = 0; i < 4; ++i)
            bad |= (((unsigned)lo[i] >> 16) ^ atag) |
                   (((unsigned)hi[i] >> 16) ^ atag);
          if (bad == 0 || --spin_budget < 0) {
            union { ushort8v u; bf16x8 bb; } c;
            #pragma unroll
            for (int i = 0; i < 4; ++i) {
              c.u[i]     = (unsigned short)lo[i];
              c.u[4 + i] = (unsigned short)hi[i];
            }
            a = c.bb;
            break;
          }
        }
      } else {
        a = *(const bf16x8*)(tsecond + (size_t)arow * HH + col);
      }
      #pragma unroll
      for (int s2 = 0; s2 < 4; ++s2) {
        bf16x8 bfr = *(const bf16x8*)(wp + (size_t)s2 * 16 * HH + kt);
        acc[s2] = MFMA_BF16(a, bfr, acc[s2]);
      }
    }
    #pragma unroll
    for (int s2 = 0; s2 < 4; ++s2) {
      int n = n_base + s2 * 16 + mrow;
      #pragma unroll
      for (int r = 0; r < 4; ++r) {
        int m = m_base + kq * 4 + r;
        size_t idx = (size_t)m * HH + n;
        float v = acc[s2][r] + emb[idx];
        if (!tfirst) {
          const int mt = m & 63, mb = m >> 6;
          const int* fp_ = ring3 + ((size_t)mt * BB + mb) * HH + n;
          const unsigned ftag = (unsigned)(sibase + mt + 1);
          for (;;) {
            unsigned fw = coh_load4(fp_);
            wait_vm0();
            __builtin_amdgcn_sched_barrier(0);
            if ((fw >> 16) == ftag || --spin_budget < 0) { v += bf2f(fw & 0xffff); break; }
          }
        } else {
          v += bf2f(tfirst[idx]);
        }
        comb_out[idx] = f2bf_rne(v);
      }
    }
  }
}

// ---------------- LayerNorm over concat([low, high]) ----------------
__global__ __launch_bounds__(256) void hrm_ln(
    const float* __restrict__ low, const float* __restrict__ high,
    const float* __restrict__ g, const float* __restrict__ bta,
    float* __restrict__ out)
{
  __shared__ float sa[256], sb[256];
  const int row = blockIdx.x;   // 0..1023
  const int tid = threadIdx.x;
  float vals[4], s = 0.f, s2 = 0.f;
  #pragma unroll
  for (int i = 0; i < 4; ++i) {
    int c = tid + i * 256;
    float v = (c < HH) ? low[(size_t)row * HH + c]
                       : high[(size_t)row * HH + (c - HH)];
    vals[i] = v; s += v; s2 += v * v;
  }
  sa[tid] = s; sb[tid] = s2; __syncthreads();
  for (int off = 128; off > 0; off >>= 1) {
    if (tid < off) { sa[tid] += sa[tid + off]; sb[tid] += sb[tid + off]; }
    __syncthreads();
  }
  float mu  = sa[0] * (1.f / 1024.f);
  float var = sb[0] * (1.f / 1024.f) - mu * mu;
  float rstd = rsqrtf(var + 1e-5f);
  #pragma unroll
  for (int i = 0; i < 4; ++i) {
    int c = tid + i * 256;
    out[(size_t)row * 1024 + c] = (vals[i] - mu) * rstd * g[c] + bta[c];
  }
}

// ---------------- host orchestration ----------------
extern "C" void kernel_launch(void* const* d_in, const int* in_sizes, int n_in,
                              void* d_out, int out_size, void* d_ws, size_t ws_size,
                              hipStream_t stream) {
  const float* x        = (const float*)d_in[0];
  const float* Wp_in    = (const float*)d_in[1];
  const float* bp_in    = (const float*)d_in[2];
  const float* low_Wih  = (const float*)d_in[3];
  const float* low_Whh  = (const float*)d_in[4];
  const float* low_bih  = (const float*)d_in[5];
  const float* low_bhh  = (const float*)d_in[6];
  const float* high_Wih = (const float*)d_in[7];
  const float* high_Whh = (const float*)d_in[8];
  const float* high_bih = (const float*)d_in[9];
  const float* high_bhh = (const float*)d_in[10];
  const float* W_lowp   = (const float*)d_in[11];
  const float* W_highp  = (const float*)d_in[12];
  const float* ln_g     = (const float*)d_in[13];
  const float* ln_b     = (const float*)d_in[14];
  const float* W1       = (const float*)d_in[15];
  const float* b1       = (const float*)d_in[16];
  const float* W2       = (const float*)d_in[17];
  const float* b2       = (const float*)d_in[18];
  const float* W3       = (const float*)d_in[19];
  const float* b3       = (const float*)d_in[20];

  char* wsp = (char*)d_ws;
  size_t off = 0;
  auto alloc = [&](size_t bytes) -> void* {
    void* p = wsp + off;
    off += (bytes + 255) & ~(size_t)255;
    return p;
  };
  const size_t WSZ = (size_t)GN * HH;
  unsigned short* wp_b   = (unsigned short*)alloc(512u * 512u * 2);
  unsigned short* lwih_b = (unsigned short*)alloc(NLAYER * WSZ * 2);
  unsigned short* lwhh_b = (unsigned short*)alloc(NLAYER * WSZ * 2);
  unsigned short* hwih_b = (unsigned short*)alloc(NLAYER * WSZ * 2);
  unsigned short* hwhh_b = (unsigned short*)alloc(NLAYER * WSZ * 2);
  unsigned short* wlp_b  = (unsigned short*)alloc(512u * 512u * 2);
  unsigned short* whp_b  = (unsigned short*)alloc(512u * 512u * 2);
  unsigned short* w1_b   = (unsigned short*)alloc(512u * 1024u * 2);
  unsigned short* w2_b   = (unsigned short*)alloc(256u * 512u * 2);
  unsigned short* w3p_b  = (unsigned short*)alloc(64u * 256u * 2);

  float* bsum_l = (float*)alloc(NLAYER * GN * 4);
  float* bsum_h = (float*)alloc(NLAYER * GN * 4);

  float* emb    = (float*)alloc((size_t)MR * HH * 4);
  float* lowb   = (float*)alloc((size_t)MR * HH * 4);
  float* highb  = (float*)alloc((size_t)MR * HH * 4);
  unsigned short* comb   = (unsigned short*)alloc((size_t)MR * HH * 2);
  unsigned short* low16  = (unsigned short*)alloc((size_t)MR * HH * 2);
  unsigned short* high16 = (unsigned short*)alloc((size_t)MR * HH * 2);
  int* hbuf = (int*)alloc((size_t)NSLOT * BB * HH * 4);
  // aliases (disjoint lifetimes): MLP temporaries reuse dead regions.
  float* normed = (float*)hbuf;                 // 4 MB of hbuf's 8.4 MB
  float* xa     = (float*)comb;                 // comb+low16 (2MB) >= xa
  float* xb     = (float*)high16;               // 1 MB

  auto cvt = [&](unsigned short* dst, const float* src, int n) {
    hrm_cvt_bf16<<<(n + 255) / 256, 256, 0, stream>>>(dst, src, n);
  };
  cvt(wp_b,   Wp_in,    512 * 512);
  cvt(lwih_b, low_Wih,  (int)(NLAYER * WSZ));
  cvt(lwhh_b, low_Whh,  (int)(NLAYER * WSZ));
  cvt(hwih_b, high_Wih, (int)(NLAYER * WSZ));
  cvt(hwhh_b, high_Whh, (int)(NLAYER * WSZ));
  cvt(wlp_b,  W_lowp,   512 * 512);
  cvt(whp_b,  W_highp,  512 * 512);
  cvt(w1_b,   W1,       512 * 1024);
  cvt(w2_b,   W2,       256 * 512);
  hrm_zero_u16<<<(64 * 256 + 255) / 256, 256, 0, stream>>>(w3p_b, 64 * 256);
  cvt(w3p_b, W3, OUTD * 256);

  hrm_addvec<<<(NLAYER * GN + 255) / 256, 256, 0, stream>>>(
      bsum_l, low_bih, low_bhh, NLAYER * GN);
  hrm_addvec<<<(NLAYER * GN + 255) / 256, 256, 0, stream>>>(
      bsum_h, high_bih, high_bhh, NLAYER * GN);

  // zero-init: tag rings (wipe poison+stale tags) and bf16 state buffers
  hrm_zero_f32<<<(NSLOT * BB * HH + 255) / 256, 256, 0, stream>>>(
      (float*)hbuf, NSLOT * BB * HH);
  hrm_zero_u16<<<(MR * HH + 255) / 256, 256, 0, stream>>>(low16,  MR * HH);
  hrm_zero_u16<<<(MR * HH + 255) / 256, 256, 0, stream>>>(high16, MR * HH);

  // emb = x @ Wp_in^T + bp_in ; comb0 = bf16(emb)
  hrm_gemm16<<<dim3(HH / 64, MR / 16), 64, 0, stream>>>(
      x, wp_b, emb, bp_in, nullptr, nullptr, nullptr, HH, HH, 0, 0);
  cvt(comb, emb, MR * HH);

  const int seq[10] = {0, 0, 0, 0, 1, 0, 0, 0, 0, 1};
  for (int si = 0; si < 10; ++si) {
    const int ty = seq[si];
    float* Yp = (si == 8) ? lowb : (si == 9) ? highb : nullptr;
    unsigned short* st16 = ty ? high16 : low16;

    const unsigned short* projw = nullptr;
    const unsigned short* tfirst = nullptr;
    const unsigned short* tsecond = nullptr;
    unsigned short* comb_out = nullptr;
    if (si < 9) {
      const int t2 = seq[si + 1];
      projw = t2 ? whp_b : wlp_b;
      // first = state(t2), second = state(!t2); fresh (ring) = state(ty)
      if (t2 != ty)        tfirst  = t2 ? high16 : low16;   // else ring
      if ((t2 ^ 1) != ty)  tsecond = t2 ? low16 : high16;   // else ring
      comb_out = comb;
    }
    hrm_stack<<<NLAYER * LBLK, 256, 0, stream>>>(
        comb, ty ? hwih_b : lwih_b, ty ? hwhh_b : lwhh_b,
        ty ? bsum_h : bsum_l, Yp, st16, hbuf, si * 64,
        projw, tfirst, tsecond, emb, comb_out);
  }

  // LayerNorm(concat) -> MLP
  hrm_ln<<<MR, 256, 0, stream>>>(lowb, highb, ln_g, ln_b, normed);
  hrm_gemm16<<<dim3(HH / 64, MR / 16), 64, 0, stream>>>(
      normed, w1_b, xa, b1, nullptr, nullptr, nullptr, HH, 2 * HH, 1, 0);
  hrm_gemm16<<<dim3(256 / 64, MR / 16), 64, 0, stream>>>(
      xa, w2_b, xb, b2, nullptr, nullptr, nullptr, 256, HH, 1, 0);
  hrm_gemm16<<<dim3(1, MR / 16), 64, 0, stream>>>(
      xb, w3p_b, (float*)d_out, b3, nullptr, nullptr, nullptr, OUTD, 256, 0, 0);
  (void)in_sizes; (void)n_in; (void)out_size; (void)ws_size;
}